// Round 8
// baseline (448.865 us; speedup 1.0000x reference)
//
#include <hip/hip_runtime.h>

// ---------------------------------------------------------------------------
// meta_model: out = (w0*sig(Ll Ll^T) + w1*sig((La La^T)*aa) + w2*sig((Lm Lm^T)*mod)
//                    - sig(Lu Lu^T)) * adj + sig(Lu Lu^T)
// with L* = mlp(feat), w = softmax(ws)
//
// R7: barrier-FREE pipelined strip-sweeper.
// R6 pinned at 2.5 TB/s because (a) per-gram fills made later fj loads
// younger than the fill -> in-order vmcnt drained the fill at every gram
// phase; (b) per-step vmcnt(0)+__syncthreads = 8-wave convoy, though the
// LDS chunks are per-wave PRIVATE. Fixes:
//   - no __syncthreads in the loop at all (per-wave LDS double buffer)
//   - issue order per step: [16 fj]->[sched_barrier]->[3 fills t+1]->
//     one counted wait vmcnt(3): retires fj(t), fills(t-1), store(t-1);
//     leaves fills(t+1) in flight for a FULL step (~1500cy cover)
//   - 256-thr blocks, launch_bounds(256,3): fi 64 + fj 64 peak ~ 160 VGPR
//   - 1024 blocks = 128 rowgroups x 8 colstrips; colstrip = bid&7 == XCD
//     under round-robin -> 1MB fj panel L2-resident per XCD
// ---------------------------------------------------------------------------

typedef __attribute__((ext_vector_type(8))) short short8;
typedef __attribute__((ext_vector_type(4))) float f32x4;

__device__ __forceinline__ unsigned short f2bf(float x) {
  union { float f; unsigned u; } v; v.f = x;
  unsigned u = v.u + 0x7FFFu + ((v.u >> 16) & 1u);   // round-to-nearest-even
  return (unsigned short)(u >> 16);
}

__device__ __forceinline__ float sigf(float x) {
  float e = __builtin_amdgcn_exp2f(-1.4426950408889634f * x);
  return __builtin_amdgcn_rcpf(1.0f + e);
}

__device__ __forceinline__ void gload_lds16(const float* g, float* l) {
  __builtin_amdgcn_global_load_lds(
      (const __attribute__((address_space(1))) void*)g,
      (__attribute__((address_space(3))) void*)l, 16, 0, 0);
}

// --------------------------- stage A0: feat -> frag -------------------------
__global__ __launch_bounds__(256) void k_featfrag(const float* __restrict__ feat,
                                                  unsigned short* __restrict__ dst) {
  int t = blockIdx.x * 256 + threadIdx.x;   // 8192 rows * 64 chunks
  int row = t >> 6, kc = t & 63;            // 8 cols per thread
  const float4* s = reinterpret_cast<const float4*>(feat + row * 512 + kc * 8);
  float4 v0 = s[0], v1 = s[1];
  short8 o;
  o[0] = f2bf(v0.x); o[1] = f2bf(v0.y); o[2] = f2bf(v0.z); o[3] = f2bf(v0.w);
  o[4] = f2bf(v1.x); o[5] = f2bf(v1.y); o[6] = f2bf(v1.z); o[7] = f2bf(v1.w);
  int mb = row >> 4, kk = kc >> 2;
  int lane = ((kc & 3) << 4) | (row & 15);
  *reinterpret_cast<short8*>(dst + ((size_t)((mb * 16 + kk) * 64 + lane)) * 8) = o;
}

// --------------------- stage A0w: W1/W2 -> B-frag layout ---------------------
__global__ __launch_bounds__(256) void k_wfrag(
    const float* __restrict__ w1_0, const float* __restrict__ w1_1,
    const float* __restrict__ w1_2, const float* __restrict__ w1_3,
    const float* __restrict__ w2_0, const float* __restrict__ w2_1,
    const float* __restrict__ w2_2, const float* __restrict__ w2_3,
    unsigned short* __restrict__ w1f, unsigned short* __restrict__ w2f) {
  int t = blockIdx.x * 256 + threadIdx.x;
  if (t < 32768) {  // W1frag: [g][kk=16][nb=8][lane=64][j=8]
    int lane = t & 63, nb = (t >> 6) & 7, kk = (t >> 9) & 15, g = t >> 13;
    const float* W = g == 0 ? w1_0 : g == 1 ? w1_1 : g == 2 ? w1_2 : w1_3;
    int q = lane >> 4, r = lane & 15;
    int col = nb * 16 + r;
    short8 o;
#pragma unroll
    for (int j = 0; j < 8; ++j) o[j] = f2bf(W[(kk * 32 + q * 8 + j) * 128 + col]);
    *reinterpret_cast<short8*>(w1f + (size_t)t * 8) = o;
  } else if (t < 40960) {  // W2frag: [g][kk=4][nb=8][lane=64][j=8]
    int t2 = t - 32768;
    int lane = t2 & 63, nb = (t2 >> 6) & 7, kk = (t2 >> 9) & 3, g = t2 >> 11;
    const float* W = g == 0 ? w2_0 : g == 1 ? w2_1 : g == 2 ? w2_2 : w2_3;
    int q = lane >> 4, r = lane & 15;
    int col = nb * 16 + r;
    short8 o;
#pragma unroll
    for (int j = 0; j < 8; ++j) o[j] = f2bf(W[(kk * 32 + q * 8 + j) * 128 + col]);
    *reinterpret_cast<short8*>(w2f + (size_t)t2 * 8) = o;
  }
}

// --------------------- stage A1: H = relu(feat@W1cat + b1) -------------------
__global__ __launch_bounds__(256) void k_gemm1(
    const unsigned short* __restrict__ featf, const unsigned short* __restrict__ w1f,
    const float* __restrict__ b1_0, const float* __restrict__ b1_1,
    const float* __restrict__ b1_2, const float* __restrict__ b1_3,
    unsigned short* __restrict__ hfrag) {
  int bi = blockIdx.x, g = blockIdx.y;
  int lane = threadIdx.x & 63, w = threadIdx.x >> 6;
  int wm = w >> 1, wn = w & 1;
  int q = lane >> 4, r = lane & 15;
  int mbase = 8 * bi + 4 * wm;

  f32x4 s[4][4];
#pragma unroll
  for (int mi = 0; mi < 4; ++mi)
#pragma unroll
    for (int nj = 0; nj < 4; ++nj) s[mi][nj] = (f32x4){0.f, 0.f, 0.f, 0.f};

  for (int kk = 0; kk < 16; ++kk) {
    short8 a[4], b[4];
#pragma unroll
    for (int mi = 0; mi < 4; ++mi)
      a[mi] = *reinterpret_cast<const short8*>(
          featf + ((size_t)(((mbase + mi) * 16 + kk) * 64 + lane)) * 8);
#pragma unroll
    for (int nj = 0; nj < 4; ++nj)
      b[nj] = *reinterpret_cast<const short8*>(
          w1f + ((size_t)(((g * 16 + kk) * 8 + 4 * wn + nj) * 64 + lane)) * 8);
#pragma unroll
    for (int mi = 0; mi < 4; ++mi)
#pragma unroll
      for (int nj = 0; nj < 4; ++nj)
        s[mi][nj] = __builtin_amdgcn_mfma_f32_16x16x32_bf16(a[mi], b[nj], s[mi][nj], 0, 0, 0);
  }

  const float* b1 = g == 0 ? b1_0 : g == 1 ? b1_1 : g == 2 ? b1_2 : b1_3;
#pragma unroll
  for (int nj = 0; nj < 4; ++nj) {
    int cl = 64 * wn + 16 * nj + r;
    float bias = b1[cl];
    int Cg = 128 * g + cl;
    int kkd = Cg >> 5;
    int lane2hi = ((Cg >> 3) & 3) << 4;
    int j2 = Cg & 7;
#pragma unroll
    for (int mi = 0; mi < 4; ++mi) {
#pragma unroll
      for (int v = 0; v < 4; ++v) {
        int R = 128 * bi + 64 * wm + 16 * mi + 4 * q + v;
        float val = fmaxf(s[mi][nj][v] + bias, 0.0f);
        int mb = R >> 4;
        int lane2 = lane2hi | (R & 15);
        hfrag[((size_t)((mb * 16 + kkd) * 64 + lane2)) * 8 + j2] = f2bf(val);
      }
    }
  }
}

// --------------------- stage A2: lat_g = H_g@W2_g + b2 -----------------------
__global__ __launch_bounds__(256) void k_gemm2(
    const unsigned short* __restrict__ hfrag, const unsigned short* __restrict__ w2f,
    const float* __restrict__ b2_0, const float* __restrict__ b2_1,
    const float* __restrict__ b2_2, const float* __restrict__ b2_3,
    unsigned short* __restrict__ latf) {
  int bi = blockIdx.x, g = blockIdx.y;
  int lane = threadIdx.x & 63, w = threadIdx.x >> 6;
  int wm = w >> 1, wn = w & 1;
  int q = lane >> 4, r = lane & 15;
  int mbase = 8 * bi + 4 * wm;

  f32x4 s[4][4];
#pragma unroll
  for (int mi = 0; mi < 4; ++mi)
#pragma unroll
    for (int nj = 0; nj < 4; ++nj) s[mi][nj] = (f32x4){0.f, 0.f, 0.f, 0.f};

#pragma unroll
  for (int kk = 0; kk < 4; ++kk) {
    short8 a[4], b[4];
#pragma unroll
    for (int mi = 0; mi < 4; ++mi)
      a[mi] = *reinterpret_cast<const short8*>(
          hfrag + ((size_t)(((mbase + mi) * 16 + 4 * g + kk) * 64 + lane)) * 8);
#pragma unroll
    for (int nj = 0; nj < 4; ++nj)
      b[nj] = *reinterpret_cast<const short8*>(
          w2f + ((size_t)(((g * 4 + kk) * 8 + 4 * wn + nj) * 64 + lane)) * 8);
#pragma unroll
    for (int mi = 0; mi < 4; ++mi)
#pragma unroll
      for (int nj = 0; nj < 4; ++nj)
        s[mi][nj] = __builtin_amdgcn_mfma_f32_16x16x32_bf16(a[mi], b[nj], s[mi][nj], 0, 0, 0);
  }

  const float* b2 = g == 0 ? b2_0 : g == 1 ? b2_1 : g == 2 ? b2_2 : b2_3;
#pragma unroll
  for (int nj = 0; nj < 4; ++nj) {
    int cl = 64 * wn + 16 * nj + r;
    float bias = b2[cl];
    int kkd = cl >> 5;
    int lane2hi = ((cl >> 3) & 3) << 4;
    int j2 = cl & 7;
#pragma unroll
    for (int mi = 0; mi < 4; ++mi) {
#pragma unroll
      for (int v = 0; v < 4; ++v) {
        int R = 128 * bi + 64 * wm + 16 * mi + 4 * q + v;
        float val = s[mi][nj][v] + bias;
        int mb = R >> 4;
        int lane2 = lane2hi | (R & 15);
        latf[((size_t)(((g * 512 + mb) * 4 + kkd) * 64 + lane2)) * 8 + j2] = f2bf(val);
      }
    }
  }
}

// --------------------------- stage B: fused context --------------------------
// Block: 256 threads = 4 waves. Wave owns 16 rows (mbi), sweeps 64 steps of
// 16 cols. s = mfma(fj, fi): lane(q,r), reg v -> out(16*mbi + r, 16*mbj+4q+v).
// LDS: per-wave private double buffer smem[buf][mat][w][256 floats]; fill
// lane l writes bytes [16l,16l+16) (global addr = compute mapping), read back
// at lane*16 -> identity, conflict-free, NO barriers needed.
__global__ __launch_bounds__(256, 3) void k_ctx(
    const unsigned short* __restrict__ latf,
    const float* __restrict__ adj, const float* __restrict__ aa,
    const float* __restrict__ mod, const float* __restrict__ wsv,
    float* __restrict__ out) {
  __shared__ float smem[2][3][4][256];   // 24 KB

  int bid = blockIdx.x;            // 1024 blocks
  int colstrip = bid & 7;          // == XCD id under round-robin dispatch
  int rowgrp = bid >> 3;           // 0..127

  int tid = threadIdx.x;
  int lane = tid & 63, w = tid >> 6;
  int q = lane >> 4, r = lane & 15;

  int mbi = rowgrp * 4 + w;        // wave's 16-row block (0..511)
  int mbj0 = colstrip * 64;        // first 16-col block of the strip

  // per-lane ew offset (compute mapping): row = 16*mbi + r, col = strip + 4q
  size_t ewoff = (size_t)(mbi * 16 + r) * 8192 + (size_t)colstrip * 1024 + 4 * q;

  // softmax(ws)
  float s0w = wsv[0], s1w = wsv[1], s2w = wsv[2];
  float mx = fmaxf(fmaxf(s0w, s1w), s2w);
  float e0 = __builtin_amdgcn_exp2f(1.4426950408889634f * (s0w - mx));
  float e1 = __builtin_amdgcn_exp2f(1.4426950408889634f * (s1w - mx));
  float e2 = __builtin_amdgcn_exp2f(1.4426950408889634f * (s2w - mx));
  float inv = __builtin_amdgcn_rcpf(e0 + e1 + e2);
  float w0 = e0 * inv, w1 = e1 * inv, w2 = e2 * inv;

  const size_t GS = (size_t)512 * 2048;   // latf elements per latent

  // ---- fi fragments: 4 latents x 4 kk, loaded once, pinned vs remat ----
  short8 fi[4][4];
#pragma unroll
  for (int g = 0; g < 4; ++g)
#pragma unroll
    for (int kk = 0; kk < 4; ++kk) {
      fi[g][kk] = *reinterpret_cast<const short8*>(
          latf + GS * g + (((size_t)mbi * 4 + kk) << 9) + lane * 8);
      asm volatile("" : "+v"(fi[g][kk]));
    }

  // ---- prologue: fill step-0 tiles into buf 0 (per-wave private) ----
  gload_lds16(aa + ewoff, &smem[0][0][w][0]);
  gload_lds16(mod + ewoff, &smem[0][1][w][0]);
  gload_lds16(adj + ewoff, &smem[0][2][w][0]);
  asm volatile("s_waitcnt vmcnt(0)" ::: "memory");

  for (int t = 0; t < 64; ++t) {
    int buf = t & 1, nbuf = buf ^ 1;
    const unsigned short* fjb =
        latf + (((size_t)(mbj0 + t) * 4) << 9) + lane * 8;

    // ---- issue ALL 16 fj loads for step t (older than the fills) ----
    short8 fj[4][4];
#pragma unroll
    for (int g = 0; g < 4; ++g)
#pragma unroll
      for (int kk = 0; kk < 4; ++kk)
        fj[g][kk] = *reinterpret_cast<const short8*>(fjb + GS * g + 512 * kk);

    // ---- issue next-step fills LAST (stay outstanding across the step) ----
    __builtin_amdgcn_sched_barrier(0);
    {
      size_t ewnext = ewoff + (size_t)(t < 63 ? t + 1 : t) * 16;
      gload_lds16(aa + ewnext, &smem[nbuf][0][w][0]);
      gload_lds16(mod + ewnext, &smem[nbuf][1][w][0]);
      gload_lds16(adj + ewnext, &smem[nbuf][2][w][0]);
    }
    // one counted wait: fj(t) done => fills(t-1)/store(t-1) (older) done;
    // fills(t+1) (younger, exactly 3) remain in flight.
    asm volatile("s_waitcnt vmcnt(3)" ::: "memory");

    f32x4 sg, o4;

    // g0: link
    sg = (f32x4){0.f, 0.f, 0.f, 0.f};
    sg = __builtin_amdgcn_mfma_f32_16x16x32_bf16(fj[0][0], fi[0][0], sg, 0, 0, 0);
    sg = __builtin_amdgcn_mfma_f32_16x16x32_bf16(fj[0][1], fi[0][1], sg, 0, 0, 0);
    sg = __builtin_amdgcn_mfma_f32_16x16x32_bf16(fj[0][2], fi[0][2], sg, 0, 0, 0);
    sg = __builtin_amdgcn_mfma_f32_16x16x32_bf16(fj[0][3], fi[0][3], sg, 0, 0, 0);
#pragma unroll
    for (int v = 0; v < 4; ++v) o4[v] = w0 * sigf(sg[v]);

    // g1: aa
    sg = (f32x4){0.f, 0.f, 0.f, 0.f};
    sg = __builtin_amdgcn_mfma_f32_16x16x32_bf16(fj[1][0], fi[1][0], sg, 0, 0, 0);
    sg = __builtin_amdgcn_mfma_f32_16x16x32_bf16(fj[1][1], fi[1][1], sg, 0, 0, 0);
    sg = __builtin_amdgcn_mfma_f32_16x16x32_bf16(fj[1][2], fi[1][2], sg, 0, 0, 0);
    sg = __builtin_amdgcn_mfma_f32_16x16x32_bf16(fj[1][3], fi[1][3], sg, 0, 0, 0);
    {
      f32x4 ew = *reinterpret_cast<const f32x4*>(&smem[buf][0][w][lane * 4]);
#pragma unroll
      for (int v = 0; v < 4; ++v) o4[v] += w1 * sigf(sg[v] * ew[v]);
    }

    // g2: mod
    sg = (f32x4){0.f, 0.f, 0.f, 0.f};
    sg = __builtin_amdgcn_mfma_f32_16x16x32_bf16(fj[2][0], fi[2][0], sg, 0, 0, 0);
    sg = __builtin_amdgcn_mfma_f32_16x16x32_bf16(fj[2][1], fi[2][1], sg, 0, 0, 0);
    sg = __builtin_amdgcn_mfma_f32_16x16x32_bf16(fj[2][2], fi[2][2], sg, 0, 0, 0);
    sg = __builtin_amdgcn_mfma_f32_16x16x32_bf16(fj[2][3], fi[2][3], sg, 0, 0, 0);
    {
      f32x4 ew = *reinterpret_cast<const f32x4*>(&smem[buf][1][w][lane * 4]);
#pragma unroll
      for (int v = 0; v < 4; ++v) o4[v] += w2 * sigf(sg[v] * ew[v]);
    }

    // g3: unlink + combine + store
    sg = (f32x4){0.f, 0.f, 0.f, 0.f};
    sg = __builtin_amdgcn_mfma_f32_16x16x32_bf16(fj[3][0], fi[3][0], sg, 0, 0, 0);
    sg = __builtin_amdgcn_mfma_f32_16x16x32_bf16(fj[3][1], fi[3][1], sg, 0, 0, 0);
    sg = __builtin_amdgcn_mfma_f32_16x16x32_bf16(fj[3][2], fi[3][2], sg, 0, 0, 0);
    sg = __builtin_amdgcn_mfma_f32_16x16x32_bf16(fj[3][3], fi[3][3], sg, 0, 0, 0);
    {
      f32x4 ew = *reinterpret_cast<const f32x4*>(&smem[buf][2][w][lane * 4]);
      f32x4 res;
#pragma unroll
      for (int v = 0; v < 4; ++v) {
        float u = sigf(sg[v]);
        res[v] = ew[v] * (o4[v] - u) + u;
      }
      __builtin_nontemporal_store(res, reinterpret_cast<f32x4*>(out + ewoff + (size_t)t * 16));
    }
  }
}

// ------------------------------------------------------------------------------
extern "C" void kernel_launch(void* const* d_in, const int* in_sizes, int n_in,
                              void* d_out, int out_size, void* d_ws, size_t ws_size,
                              hipStream_t stream) {
  const float* feat = (const float*)d_in[0];
  const float* adj  = (const float*)d_in[1];
  const float* aa   = (const float*)d_in[2];
  const float* mod  = (const float*)d_in[3];
  // g order: 0=link, 1=aa, 2=mod, 3=unlink
  const float* W1g[4] = {(const float*)d_in[4], (const float*)d_in[12],
                         (const float*)d_in[16], (const float*)d_in[8]};
  const float* b1g[4] = {(const float*)d_in[5], (const float*)d_in[13],
                         (const float*)d_in[17], (const float*)d_in[9]};
  const float* W2g[4] = {(const float*)d_in[6], (const float*)d_in[14],
                         (const float*)d_in[18], (const float*)d_in[10]};
  const float* b2g[4] = {(const float*)d_in[7], (const float*)d_in[15],
                         (const float*)d_in[19], (const float*)d_in[11]};
  const float* wsv = (const float*)d_in[20];
  float* out = (float*)d_out;

  // workspace layout (elements of ushort)
  unsigned short* featf = (unsigned short*)d_ws;   // 4,194,304 elems (8 MiB)
  unsigned short* hfrag = featf + 4194304;         // 4,194,304
  unsigned short* latf  = hfrag + 4194304;         // 4,194,304
  unsigned short* w1f   = latf + 4194304;          //   262,144
  unsigned short* w2f   = w1f + 262144;            //    65,536
  if (ws_size < 25821184) return;

  k_featfrag<<<2048, 256, 0, stream>>>(feat, featf);
  k_wfrag<<<160, 256, 0, stream>>>(W1g[0], W1g[1], W1g[2], W1g[3],
                                   W2g[0], W2g[1], W2g[2], W2g[3], w1f, w2f);
  k_gemm1<<<dim3(64, 4), 256, 0, stream>>>(featf, w1f, b1g[0], b1g[1], b1g[2], b1g[3], hfrag);
  k_gemm2<<<dim3(64, 4), 256, 0, stream>>>(hfrag, w2f, b2g[0], b2g[1], b2g[2], b2g[3], latf);
  k_ctx<<<1024, 256, 0, stream>>>(latf, adj, aa, mod, wsv, out);
}

// Round 9
// 396.874 us; speedup vs baseline: 1.1310x; 1.1310x over previous
//
#include <hip/hip_runtime.h>

// ---------------------------------------------------------------------------
// meta_model: out = (w0*sig(Ll Ll^T) + w1*sig((La La^T)*aa) + w2*sig((Lm Lm^T)*mod)
//                    - sig(Lu Lu^T)) * adj + sig(Lu Lu^T)
// with L* = mlp(feat), w = softmax(ws)
//
// R8: DRAM-pattern fix. R1-R7 (five schedules, occ 17-45%) all pinned at
// 2.2-2.9 TB/s because every one read ew tiles at 64 B per row x 32 KB row
// stride -> one DRAM burst per page activation (~40% of copy BW). New k_ctx:
//   - block = 512 thr (8 waves) owns 16 rows x 128 cols per superstep
//   - ew fills are ROW-LINEAR: each global_load_lds = 1 KB = 2 rows x 512 B
//     contiguous (8x page-activation amortization)
//   - per wave: 1 output tile (16x16) per superstep; fj = 16 frags (128 VGPR)
//     preloaded BEFORE the 3 fills -> counted vmcnt(3) never drains fills
//   - fi staged in LDS once (shared by all 8 waves); ALL in-loop LDS reads
//     are inline-asm ds_read_b128 (opaque to the aliasing-paranoid waitcnt
//     pass) + manual lgkmcnt(0)+sched_barrier (rule 18)
//   - raw s_barrier + vmcnt(1) per superstep (fills done, store in flight);
//     no __syncthreads auto vmcnt(0) drain
//   - plain stores: adjacent waves cover each 128-B line -> L2 write-combine
// ---------------------------------------------------------------------------

typedef __attribute__((ext_vector_type(8))) short short8;
typedef __attribute__((ext_vector_type(4))) float f32x4;

__device__ __forceinline__ unsigned short f2bf(float x) {
  union { float f; unsigned u; } v; v.f = x;
  unsigned u = v.u + 0x7FFFu + ((v.u >> 16) & 1u);   // round-to-nearest-even
  return (unsigned short)(u >> 16);
}

__device__ __forceinline__ float sigf(float x) {
  float e = __builtin_amdgcn_exp2f(-1.4426950408889634f * x);
  return __builtin_amdgcn_rcpf(1.0f + e);
}

__device__ __forceinline__ void gload_lds16(const float* g, float* l) {
  __builtin_amdgcn_global_load_lds(
      (const __attribute__((address_space(1))) void*)g,
      (__attribute__((address_space(3))) void*)l, 16, 0, 0);
}
__device__ __forceinline__ void gload_lds16u(const unsigned short* g, unsigned short* l) {
  __builtin_amdgcn_global_load_lds(
      (const __attribute__((address_space(1))) void*)g,
      (__attribute__((address_space(3))) void*)l, 16, 0, 0);
}

__device__ __forceinline__ unsigned lds_off(const void* p) {
  return (unsigned)(uintptr_t)(const __attribute__((address_space(3))) void*)p;
}
__device__ __forceinline__ f32x4 ds_read_f32x4(unsigned a) {
  f32x4 d;
  asm volatile("ds_read_b128 %0, %1" : "=v"(d) : "v"(a));
  return d;
}
__device__ __forceinline__ short8 ds_read_frag(unsigned a) {
  short8 d;
  asm volatile("ds_read_b128 %0, %1" : "=v"(d) : "v"(a));
  return d;
}

// --------------------------- stage A0: feat -> frag -------------------------
__global__ __launch_bounds__(256) void k_featfrag(const float* __restrict__ feat,
                                                  unsigned short* __restrict__ dst) {
  int t = blockIdx.x * 256 + threadIdx.x;   // 8192 rows * 64 chunks
  int row = t >> 6, kc = t & 63;            // 8 cols per thread
  const float4* s = reinterpret_cast<const float4*>(feat + row * 512 + kc * 8);
  float4 v0 = s[0], v1 = s[1];
  short8 o;
  o[0] = f2bf(v0.x); o[1] = f2bf(v0.y); o[2] = f2bf(v0.z); o[3] = f2bf(v0.w);
  o[4] = f2bf(v1.x); o[5] = f2bf(v1.y); o[6] = f2bf(v1.z); o[7] = f2bf(v1.w);
  int mb = row >> 4, kk = kc >> 2;
  int lane = ((kc & 3) << 4) | (row & 15);
  *reinterpret_cast<short8*>(dst + ((size_t)((mb * 16 + kk) * 64 + lane)) * 8) = o;
}

// --------------------- stage A0w: W1/W2 -> B-frag layout ---------------------
__global__ __launch_bounds__(256) void k_wfrag(
    const float* __restrict__ w1_0, const float* __restrict__ w1_1,
    const float* __restrict__ w1_2, const float* __restrict__ w1_3,
    const float* __restrict__ w2_0, const float* __restrict__ w2_1,
    const float* __restrict__ w2_2, const float* __restrict__ w2_3,
    unsigned short* __restrict__ w1f, unsigned short* __restrict__ w2f) {
  int t = blockIdx.x * 256 + threadIdx.x;
  if (t < 32768) {  // W1frag: [g][kk=16][nb=8][lane=64][j=8]
    int lane = t & 63, nb = (t >> 6) & 7, kk = (t >> 9) & 15, g = t >> 13;
    const float* W = g == 0 ? w1_0 : g == 1 ? w1_1 : g == 2 ? w1_2 : w1_3;
    int q = lane >> 4, r = lane & 15;
    int col = nb * 16 + r;
    short8 o;
#pragma unroll
    for (int j = 0; j < 8; ++j) o[j] = f2bf(W[(kk * 32 + q * 8 + j) * 128 + col]);
    *reinterpret_cast<short8*>(w1f + (size_t)t * 8) = o;
  } else if (t < 40960) {  // W2frag: [g][kk=4][nb=8][lane=64][j=8]
    int t2 = t - 32768;
    int lane = t2 & 63, nb = (t2 >> 6) & 7, kk = (t2 >> 9) & 3, g = t2 >> 11;
    const float* W = g == 0 ? w2_0 : g == 1 ? w2_1 : g == 2 ? w2_2 : w2_3;
    int q = lane >> 4, r = lane & 15;
    int col = nb * 16 + r;
    short8 o;
#pragma unroll
    for (int j = 0; j < 8; ++j) o[j] = f2bf(W[(kk * 32 + q * 8 + j) * 128 + col]);
    *reinterpret_cast<short8*>(w2f + (size_t)t2 * 8) = o;
  }
}

// --------------------- stage A1: H = relu(feat@W1cat + b1) -------------------
__global__ __launch_bounds__(256) void k_gemm1(
    const unsigned short* __restrict__ featf, const unsigned short* __restrict__ w1f,
    const float* __restrict__ b1_0, const float* __restrict__ b1_1,
    const float* __restrict__ b1_2, const float* __restrict__ b1_3,
    unsigned short* __restrict__ hfrag) {
  int bi = blockIdx.x, g = blockIdx.y;
  int lane = threadIdx.x & 63, w = threadIdx.x >> 6;
  int wm = w >> 1, wn = w & 1;
  int q = lane >> 4, r = lane & 15;
  int mbase = 8 * bi + 4 * wm;

  f32x4 s[4][4];
#pragma unroll
  for (int mi = 0; mi < 4; ++mi)
#pragma unroll
    for (int nj = 0; nj < 4; ++nj) s[mi][nj] = (f32x4){0.f, 0.f, 0.f, 0.f};

  for (int kk = 0; kk < 16; ++kk) {
    short8 a[4], b[4];
#pragma unroll
    for (int mi = 0; mi < 4; ++mi)
      a[mi] = *reinterpret_cast<const short8*>(
          featf + ((size_t)(((mbase + mi) * 16 + kk) * 64 + lane)) * 8);
#pragma unroll
    for (int nj = 0; nj < 4; ++nj)
      b[nj] = *reinterpret_cast<const short8*>(
          w1f + ((size_t)(((g * 16 + kk) * 8 + 4 * wn + nj) * 64 + lane)) * 8);
#pragma unroll
    for (int mi = 0; mi < 4; ++mi)
#pragma unroll
      for (int nj = 0; nj < 4; ++nj)
        s[mi][nj] = __builtin_amdgcn_mfma_f32_16x16x32_bf16(a[mi], b[nj], s[mi][nj], 0, 0, 0);
  }

  const float* b1 = g == 0 ? b1_0 : g == 1 ? b1_1 : g == 2 ? b1_2 : b1_3;
#pragma unroll
  for (int nj = 0; nj < 4; ++nj) {
    int cl = 64 * wn + 16 * nj + r;
    float bias = b1[cl];
    int Cg = 128 * g + cl;
    int kkd = Cg >> 5;
    int lane2hi = ((Cg >> 3) & 3) << 4;
    int j2 = Cg & 7;
#pragma unroll
    for (int mi = 0; mi < 4; ++mi) {
#pragma unroll
      for (int v = 0; v < 4; ++v) {
        int R = 128 * bi + 64 * wm + 16 * mi + 4 * q + v;
        float val = fmaxf(s[mi][nj][v] + bias, 0.0f);
        int mb = R >> 4;
        int lane2 = lane2hi | (R & 15);
        hfrag[((size_t)((mb * 16 + kkd) * 64 + lane2)) * 8 + j2] = f2bf(val);
      }
    }
  }
}

// --------------------- stage A2: lat_g = H_g@W2_g + b2 -----------------------
__global__ __launch_bounds__(256) void k_gemm2(
    const unsigned short* __restrict__ hfrag, const unsigned short* __restrict__ w2f,
    const float* __restrict__ b2_0, const float* __restrict__ b2_1,
    const float* __restrict__ b2_2, const float* __restrict__ b2_3,
    unsigned short* __restrict__ latf) {
  int bi = blockIdx.x, g = blockIdx.y;
  int lane = threadIdx.x & 63, w = threadIdx.x >> 6;
  int wm = w >> 1, wn = w & 1;
  int q = lane >> 4, r = lane & 15;
  int mbase = 8 * bi + 4 * wm;

  f32x4 s[4][4];
#pragma unroll
  for (int mi = 0; mi < 4; ++mi)
#pragma unroll
    for (int nj = 0; nj < 4; ++nj) s[mi][nj] = (f32x4){0.f, 0.f, 0.f, 0.f};

#pragma unroll
  for (int kk = 0; kk < 4; ++kk) {
    short8 a[4], b[4];
#pragma unroll
    for (int mi = 0; mi < 4; ++mi)
      a[mi] = *reinterpret_cast<const short8*>(
          hfrag + ((size_t)(((mbase + mi) * 16 + 4 * g + kk) * 64 + lane)) * 8);
#pragma unroll
    for (int nj = 0; nj < 4; ++nj)
      b[nj] = *reinterpret_cast<const short8*>(
          w2f + ((size_t)(((g * 4 + kk) * 8 + 4 * wn + nj) * 64 + lane)) * 8);
#pragma unroll
    for (int mi = 0; mi < 4; ++mi)
#pragma unroll
      for (int nj = 0; nj < 4; ++nj)
        s[mi][nj] = __builtin_amdgcn_mfma_f32_16x16x32_bf16(a[mi], b[nj], s[mi][nj], 0, 0, 0);
  }

  const float* b2 = g == 0 ? b2_0 : g == 1 ? b2_1 : g == 2 ? b2_2 : b2_3;
#pragma unroll
  for (int nj = 0; nj < 4; ++nj) {
    int cl = 64 * wn + 16 * nj + r;
    float bias = b2[cl];
    int kkd = cl >> 5;
    int lane2hi = ((cl >> 3) & 3) << 4;
    int j2 = cl & 7;
#pragma unroll
    for (int mi = 0; mi < 4; ++mi) {
#pragma unroll
      for (int v = 0; v < 4; ++v) {
        int R = 128 * bi + 64 * wm + 16 * mi + 4 * q + v;
        float val = s[mi][nj][v] + bias;
        int mb = R >> 4;
        int lane2 = lane2hi | (R & 15);
        latf[((size_t)(((g * 512 + mb) * 4 + kkd) * 64 + lane2)) * 8 + j2] = f2bf(val);
      }
    }
  }
}

// --------------------------- stage B: fused context --------------------------
// Block: 512 thr = 8 waves; block tile = 16 rows (mbi=bid) x 128 cols per
// superstep, 64 supersteps. Wave w owns col tile jj = s*8 + w.
// s = mfma(fj, fi): lane(q,r) reg v -> out(16*mbi + r, 16*jj + 4q + v).
// LDS: fi (16 KB, 16 frag-slots, lane-linear); ew dbuf [2][3][2048 f32] where
// pair p=rows{2p,2p+1} sits at floats [256p,256p+256) (row-linear fills:
// 1 gload_lds = 2 rows x 512 B contiguous). 64 KB total.
__global__ __launch_bounds__(512, 2) void k_ctx(
    const unsigned short* __restrict__ latf,
    const float* __restrict__ adj, const float* __restrict__ aa,
    const float* __restrict__ mod, const float* __restrict__ wsv,
    float* __restrict__ out) {
  __shared__ unsigned short fi_lds[8192];    // 16 KB
  __shared__ float ew_lds[2][3][2048];       // 48 KB

  int bid = blockIdx.x;                      // 512 blocks = mbi
  int tid = threadIdx.x;
  int lane = tid & 63, w = tid >> 6;         // 8 waves
  int q = lane >> 4, r = lane & 15;
  int mbi = bid;

  // softmax(ws)
  float s0w = wsv[0], s1w = wsv[1], s2w = wsv[2];
  float mx = fmaxf(fmaxf(s0w, s1w), s2w);
  float e0 = __builtin_amdgcn_exp2f(1.4426950408889634f * (s0w - mx));
  float e1 = __builtin_amdgcn_exp2f(1.4426950408889634f * (s1w - mx));
  float e2 = __builtin_amdgcn_exp2f(1.4426950408889634f * (s2w - mx));
  float inv = __builtin_amdgcn_rcpf(e0 + e1 + e2);
  float w0 = e0 * inv, w1 = e1 * inv, w2 = e2 * inv;

  const size_t GS = (size_t)512 * 2048;      // latf elements per latent

  // ---- prologue: stage fi (16 x 1KB, wave w does slots 2w, 2w+1) ----
#pragma unroll
  for (int e = 0; e < 2; ++e) {
    int i = 2 * w + e;
    int g = i >> 2, kk = i & 3;
    gload_lds16u(latf + GS * g + (size_t)(mbi * 4 + kk) * 512 + lane * 8,
                 &fi_lds[i * 512]);
  }
  // ---- prologue: ew fill s=0 (row-linear: 2 rows x 512 B per instr) ----
  size_t rowbase = (size_t)(mbi * 16 + 2 * w + (lane >> 5)) * 8192 + (lane & 31) * 4;
  gload_lds16(aa + rowbase, &ew_lds[0][0][w * 256]);
  gload_lds16(mod + rowbase, &ew_lds[0][1][w * 256]);
  gload_lds16(adj + rowbase, &ew_lds[0][2][w * 256]);
  asm volatile("s_waitcnt vmcnt(0)" ::: "memory");
  __builtin_amdgcn_s_barrier();

  unsigned fib = lds_off(fi_lds);
  unsigned ewb = lds_off(&ew_lds[0][0][0]);
  unsigned l16 = (unsigned)lane * 16u;
  // ew read addr (bytes): pair r>>1, parity r&1, col 16w+4q
  unsigned ewlane = (unsigned)(((r >> 1) * 256 + (r & 1) * 128 + 16 * w + 4 * q) * 4);

#pragma unroll 1
  for (int s = 0; s < 64; ++s) {
    int buf = s & 1, nbuf = buf ^ 1;

    // ---- P: all 16 fj loads for this superstep (oldest in vmcnt queue) ----
    const unsigned short* fjb =
        latf + (size_t)((s * 8 + w) * 4) * 512 + lane * 8;
    short8 fj[4][4];
#pragma unroll
    for (int g = 0; g < 4; ++g)
#pragma unroll
      for (int kk = 0; kk < 4; ++kk)
        fj[g][kk] = *reinterpret_cast<const short8*>(fjb + GS * g + 512 * kk);

    __builtin_amdgcn_sched_barrier(0);

    // ---- F: fills for s+1 (youngest; never drained mid-superstep) ----
    {
      int s1 = (s < 63) ? s + 1 : s;
      size_t fs = rowbase + (size_t)s1 * 128;
      gload_lds16(aa + fs, &ew_lds[nbuf][0][w * 256]);
      gload_lds16(mod + fs, &ew_lds[nbuf][1][w * 256]);
      gload_lds16(adj + fs, &ew_lds[nbuf][2][w * 256]);
    }
    __builtin_amdgcn_sched_barrier(0);
    // fj done (retires prev store too); 3 fills remain in flight
    asm volatile("s_waitcnt vmcnt(3)" ::: "memory");
    __builtin_amdgcn_sched_barrier(0);

    // ---- ew reads from current buffer (asm, lgkm-counted) ----
    unsigned ewc = ewb + (unsigned)buf * 24576u + ewlane;
    f32x4 ewa = ds_read_f32x4(ewc);
    f32x4 ewm = ds_read_f32x4(ewc + 8192u);
    f32x4 ewj = ds_read_f32x4(ewc + 16384u);

    f32x4 sg, o4;

    // ---------------- g0: link ----------------
    {
      short8 f0 = ds_read_frag(fib + 0 * 1024 + l16);
      short8 f1 = ds_read_frag(fib + 1 * 1024 + l16);
      short8 f2 = ds_read_frag(fib + 2 * 1024 + l16);
      short8 f3 = ds_read_frag(fib + 3 * 1024 + l16);
      asm volatile("s_waitcnt lgkmcnt(0)" ::: "memory");
      __builtin_amdgcn_sched_barrier(0);
      sg = (f32x4){0.f, 0.f, 0.f, 0.f};
      sg = __builtin_amdgcn_mfma_f32_16x16x32_bf16(fj[0][0], f0, sg, 0, 0, 0);
      sg = __builtin_amdgcn_mfma_f32_16x16x32_bf16(fj[0][1], f1, sg, 0, 0, 0);
      sg = __builtin_amdgcn_mfma_f32_16x16x32_bf16(fj[0][2], f2, sg, 0, 0, 0);
      sg = __builtin_amdgcn_mfma_f32_16x16x32_bf16(fj[0][3], f3, sg, 0, 0, 0);
#pragma unroll
      for (int v = 0; v < 4; ++v) o4[v] = w0 * sigf(sg[v]);
    }

    // ---------------- g1: aa ----------------
    {
      short8 f0 = ds_read_frag(fib + 4 * 1024 + l16);
      short8 f1 = ds_read_frag(fib + 5 * 1024 + l16);
      short8 f2 = ds_read_frag(fib + 6 * 1024 + l16);
      short8 f3 = ds_read_frag(fib + 7 * 1024 + l16);
      asm volatile("s_waitcnt lgkmcnt(0)" ::: "memory");
      __builtin_amdgcn_sched_barrier(0);
      sg = (f32x4){0.f, 0.f, 0.f, 0.f};
      sg = __builtin_amdgcn_mfma_f32_16x16x32_bf16(fj[1][0], f0, sg, 0, 0, 0);
      sg = __builtin_amdgcn_mfma_f32_16x16x32_bf16(fj[1][1], f1, sg, 0, 0, 0);
      sg = __builtin_amdgcn_mfma_f32_16x16x32_bf16(fj[1][2], f2, sg, 0, 0, 0);
      sg = __builtin_amdgcn_mfma_f32_16x16x32_bf16(fj[1][3], f3, sg, 0, 0, 0);
#pragma unroll
      for (int v = 0; v < 4; ++v) o4[v] += w1 * sigf(sg[v] * ewa[v]);
    }

    // ---------------- g2: mod ----------------
    {
      short8 f0 = ds_read_frag(fib + 8 * 1024 + l16);
      short8 f1 = ds_read_frag(fib + 9 * 1024 + l16);
      short8 f2 = ds_read_frag(fib + 10 * 1024 + l16);
      short8 f3 = ds_read_frag(fib + 11 * 1024 + l16);
      asm volatile("s_waitcnt lgkmcnt(0)" ::: "memory");
      __builtin_amdgcn_sched_barrier(0);
      sg = (f32x4){0.f, 0.f, 0.f, 0.f};
      sg = __builtin_amdgcn_mfma_f32_16x16x32_bf16(fj[2][0], f0, sg, 0, 0, 0);
      sg = __builtin_amdgcn_mfma_f32_16x16x32_bf16(fj[2][1], f1, sg, 0, 0, 0);
      sg = __builtin_amdgcn_mfma_f32_16x16x32_bf16(fj[2][2], f2, sg, 0, 0, 0);
      sg = __builtin_amdgcn_mfma_f32_16x16x32_bf16(fj[2][3], f3, sg, 0, 0, 0);
#pragma unroll
      for (int v = 0; v < 4; ++v) o4[v] += w2 * sigf(sg[v] * ewm[v]);
    }

    // ---------------- g3: unlink + combine + store ----------------
    {
      short8 f0 = ds_read_frag(fib + 12 * 1024 + l16);
      short8 f1 = ds_read_frag(fib + 13 * 1024 + l16);
      short8 f2 = ds_read_frag(fib + 14 * 1024 + l16);
      short8 f3 = ds_read_frag(fib + 15 * 1024 + l16);
      asm volatile("s_waitcnt lgkmcnt(0)" ::: "memory");
      __builtin_amdgcn_sched_barrier(0);
      sg = (f32x4){0.f, 0.f, 0.f, 0.f};
      sg = __builtin_amdgcn_mfma_f32_16x16x32_bf16(fj[3][0], f0, sg, 0, 0, 0);
      sg = __builtin_amdgcn_mfma_f32_16x16x32_bf16(fj[3][1], f1, sg, 0, 0, 0);
      sg = __builtin_amdgcn_mfma_f32_16x16x32_bf16(fj[3][2], f2, sg, 0, 0, 0);
      sg = __builtin_amdgcn_mfma_f32_16x16x32_bf16(fj[3][3], f3, sg, 0, 0, 0);
      f32x4 res;
#pragma unroll
      for (int v = 0; v < 4; ++v) {
        float u = sigf(sg[v]);
        res[v] = ewj[v] * (o4[v] - u) + u;
      }
      size_t outoff = (size_t)(mbi * 16 + r) * 8192 + s * 128 + 16 * w + 4 * q;
      *reinterpret_cast<f32x4*>(out + outoff) = res;
    }

    // fills(s+1) complete (store may still be in flight), then barrier
    asm volatile("s_waitcnt vmcnt(1)" ::: "memory");
    __builtin_amdgcn_s_barrier();
  }
}

// ------------------------------------------------------------------------------
extern "C" void kernel_launch(void* const* d_in, const int* in_sizes, int n_in,
                              void* d_out, int out_size, void* d_ws, size_t ws_size,
                              hipStream_t stream) {
  const float* feat = (const float*)d_in[0];
  const float* adj  = (const float*)d_in[1];
  const float* aa   = (const float*)d_in[2];
  const float* mod  = (const float*)d_in[3];
  // g order: 0=link, 1=aa, 2=mod, 3=unlink
  const float* W1g[4] = {(const float*)d_in[4], (const float*)d_in[12],
                         (const float*)d_in[16], (const float*)d_in[8]};
  const float* b1g[4] = {(const float*)d_in[5], (const float*)d_in[13],
                         (const float*)d_in[17], (const float*)d_in[9]};
  const float* W2g[4] = {(const float*)d_in[6], (const float*)d_in[14],
                         (const float*)d_in[18], (const float*)d_in[10]};
  const float* b2g[4] = {(const float*)d_in[7], (const float*)d_in[15],
                         (const float*)d_in[19], (const float*)d_in[11]};
  const float* wsv = (const float*)d_in[20];
  float* out = (float*)d_out;

  // workspace layout (elements of ushort)
  unsigned short* featf = (unsigned short*)d_ws;   // 4,194,304 elems (8 MiB)
  unsigned short* hfrag = featf + 4194304;         // 4,194,304
  unsigned short* latf  = hfrag + 4194304;         // 4,194,304
  unsigned short* w1f   = latf + 4194304;          //   262,144
  unsigned short* w2f   = w1f + 262144;            //    65,536
  if (ws_size < 25821184) return;

  k_featfrag<<<2048, 256, 0, stream>>>(feat, featf);
  k_wfrag<<<160, 256, 0, stream>>>(W1g[0], W1g[1], W1g[2], W1g[3],
                                   W2g[0], W2g[1], W2g[2], W2g[3], w1f, w2f);
  k_gemm1<<<dim3(64, 4), 256, 0, stream>>>(featf, w1f, b1g[0], b1g[1], b1g[2], b1g[3], hfrag);
  k_gemm2<<<dim3(64, 4), 256, 0, stream>>>(hfrag, w2f, b2g[0], b2g[1], b2g[2], b2g[3], latf);
  k_ctx<<<512, 512, 0, stream>>>(latf, adj, aa, mod, wsv, out);
}

// Round 10
// 361.330 us; speedup vs baseline: 1.2423x; 1.0984x over previous
//
#include <hip/hip_runtime.h>

// ---------------------------------------------------------------------------
// meta_model: out = (w0*sig(Ll Ll^T) + w1*sig((La La^T)*aa) + w2*sig((Lm Lm^T)*mod)
//                    - sig(Lu Lu^T)) * adj + sig(Lu Lu^T)
// with L* = mlp(feat), w = softmax(ws)
//
// R9: fully hand-scheduled k_ctx (all in-loop vmem/LDS ops are inline asm;
// the compiler inserts NO waitcnts of its own). Fixes R8's three failures:
//   - fj frags double-buffered in REGISTERS via asm global_load_dwordx4:
//     asm defs cannot be remat'd/sunk (ends the VGPR=56/60/84 fights).
//     fj(s+1) loaded during step s -> one full step of L2/L3 cover.
//   - ew TRIPLE-buffered in LDS, filled 2 steps ahead by global_load_lds
//     (row-linear 256B/row source, page-friendly like R8).
//   - exactly two counted waits per step:
//       vmcnt(23) pre-compute: retires fj(s) (+ ew(s) long ago); keeps
//                  ew(s+1), ew(s+2), fj(s+1) in flight
//       vmcnt(21) pre-barrier: retires ew(s+1) (issued 1 step earlier,
//                  ~1.5 steps of cover); keeps fj(s+1)+ew(s+2) in flight
//   - ew bank swizzle: source col ^= 4*(row&7) floats, read addr matches
//     -> even 8-lane/4-bank-group distribution (structural only)
//   - block = 256 thr / 4 waves; wave owns one 16x16 col tile per step;
//     block = 16 rows x 2048-col strip, 32 steps; grid 2048 = 512 x 4.
// ---------------------------------------------------------------------------

typedef __attribute__((ext_vector_type(8))) short short8;
typedef __attribute__((ext_vector_type(4))) float f32x4;

__device__ __forceinline__ unsigned short f2bf(float x) {
  union { float f; unsigned u; } v; v.f = x;
  unsigned u = v.u + 0x7FFFu + ((v.u >> 16) & 1u);   // round-to-nearest-even
  return (unsigned short)(u >> 16);
}

__device__ __forceinline__ float sigf(float x) {
  float e = __builtin_amdgcn_exp2f(-1.4426950408889634f * x);
  return __builtin_amdgcn_rcpf(1.0f + e);
}

__device__ __forceinline__ void gload_lds16(const float* g, float* l) {
  __builtin_amdgcn_global_load_lds(
      (const __attribute__((address_space(1))) void*)g,
      (__attribute__((address_space(3))) void*)l, 16, 0, 0);
}
__device__ __forceinline__ void gload_lds16u(const unsigned short* g, unsigned short* l) {
  __builtin_amdgcn_global_load_lds(
      (const __attribute__((address_space(1))) void*)g,
      (__attribute__((address_space(3))) void*)l, 16, 0, 0);
}

__device__ __forceinline__ unsigned lds_off(const void* p) {
  return (unsigned)(uintptr_t)(const __attribute__((address_space(3))) void*)p;
}
__device__ __forceinline__ f32x4 ds_read_f32x4(unsigned a) {
  f32x4 d;
  asm volatile("ds_read_b128 %0, %1" : "=v"(d) : "v"(a));
  return d;
}
__device__ __forceinline__ short8 ds_read_frag(unsigned a) {
  short8 d;
  asm volatile("ds_read_b128 %0, %1" : "=v"(d) : "v"(a));
  return d;
}

// --------------------------- stage A0: feat -> frag -------------------------
__global__ __launch_bounds__(256) void k_featfrag(const float* __restrict__ feat,
                                                  unsigned short* __restrict__ dst) {
  int t = blockIdx.x * 256 + threadIdx.x;   // 8192 rows * 64 chunks
  int row = t >> 6, kc = t & 63;            // 8 cols per thread
  const float4* s = reinterpret_cast<const float4*>(feat + row * 512 + kc * 8);
  float4 v0 = s[0], v1 = s[1];
  short8 o;
  o[0] = f2bf(v0.x); o[1] = f2bf(v0.y); o[2] = f2bf(v0.z); o[3] = f2bf(v0.w);
  o[4] = f2bf(v1.x); o[5] = f2bf(v1.y); o[6] = f2bf(v1.z); o[7] = f2bf(v1.w);
  int mb = row >> 4, kk = kc >> 2;
  int lane = ((kc & 3) << 4) | (row & 15);
  *reinterpret_cast<short8*>(dst + ((size_t)((mb * 16 + kk) * 64 + lane)) * 8) = o;
}

// --------------------- stage A0w: W1/W2 -> B-frag layout ---------------------
__global__ __launch_bounds__(256) void k_wfrag(
    const float* __restrict__ w1_0, const float* __restrict__ w1_1,
    const float* __restrict__ w1_2, const float* __restrict__ w1_3,
    const float* __restrict__ w2_0, const float* __restrict__ w2_1,
    const float* __restrict__ w2_2, const float* __restrict__ w2_3,
    unsigned short* __restrict__ w1f, unsigned short* __restrict__ w2f) {
  int t = blockIdx.x * 256 + threadIdx.x;
  if (t < 32768) {  // W1frag: [g][kk=16][nb=8][lane=64][j=8]
    int lane = t & 63, nb = (t >> 6) & 7, kk = (t >> 9) & 15, g = t >> 13;
    const float* W = g == 0 ? w1_0 : g == 1 ? w1_1 : g == 2 ? w1_2 : w1_3;
    int q = lane >> 4, r = lane & 15;
    int col = nb * 16 + r;
    short8 o;
#pragma unroll
    for (int j = 0; j < 8; ++j) o[j] = f2bf(W[(kk * 32 + q * 8 + j) * 128 + col]);
    *reinterpret_cast<short8*>(w1f + (size_t)t * 8) = o;
  } else if (t < 40960) {  // W2frag: [g][kk=4][nb=8][lane=64][j=8]
    int t2 = t - 32768;
    int lane = t2 & 63, nb = (t2 >> 6) & 7, kk = (t2 >> 9) & 3, g = t2 >> 11;
    const float* W = g == 0 ? w2_0 : g == 1 ? w2_1 : g == 2 ? w2_2 : w2_3;
    int q = lane >> 4, r = lane & 15;
    int col = nb * 16 + r;
    short8 o;
#pragma unroll
    for (int j = 0; j < 8; ++j) o[j] = f2bf(W[(kk * 32 + q * 8 + j) * 128 + col]);
    *reinterpret_cast<short8*>(w2f + (size_t)t2 * 8) = o;
  }
}

// --------------------- stage A1: H = relu(feat@W1cat + b1) -------------------
__global__ __launch_bounds__(256) void k_gemm1(
    const unsigned short* __restrict__ featf, const unsigned short* __restrict__ w1f,
    const float* __restrict__ b1_0, const float* __restrict__ b1_1,
    const float* __restrict__ b1_2, const float* __restrict__ b1_3,
    unsigned short* __restrict__ hfrag) {
  int bi = blockIdx.x, g = blockIdx.y;
  int lane = threadIdx.x & 63, w = threadIdx.x >> 6;
  int wm = w >> 1, wn = w & 1;
  int q = lane >> 4, r = lane & 15;
  int mbase = 8 * bi + 4 * wm;

  f32x4 s[4][4];
#pragma unroll
  for (int mi = 0; mi < 4; ++mi)
#pragma unroll
    for (int nj = 0; nj < 4; ++nj) s[mi][nj] = (f32x4){0.f, 0.f, 0.f, 0.f};

  for (int kk = 0; kk < 16; ++kk) {
    short8 a[4], b[4];
#pragma unroll
    for (int mi = 0; mi < 4; ++mi)
      a[mi] = *reinterpret_cast<const short8*>(
          featf + ((size_t)(((mbase + mi) * 16 + kk) * 64 + lane)) * 8);
#pragma unroll
    for (int nj = 0; nj < 4; ++nj)
      b[nj] = *reinterpret_cast<const short8*>(
          w1f + ((size_t)(((g * 16 + kk) * 8 + 4 * wn + nj) * 64 + lane)) * 8);
#pragma unroll
    for (int mi = 0; mi < 4; ++mi)
#pragma unroll
      for (int nj = 0; nj < 4; ++nj)
        s[mi][nj] = __builtin_amdgcn_mfma_f32_16x16x32_bf16(a[mi], b[nj], s[mi][nj], 0, 0, 0);
  }

  const float* b1 = g == 0 ? b1_0 : g == 1 ? b1_1 : g == 2 ? b1_2 : b1_3;
#pragma unroll
  for (int nj = 0; nj < 4; ++nj) {
    int cl = 64 * wn + 16 * nj + r;
    float bias = b1[cl];
    int Cg = 128 * g + cl;
    int kkd = Cg >> 5;
    int lane2hi = ((Cg >> 3) & 3) << 4;
    int j2 = Cg & 7;
#pragma unroll
    for (int mi = 0; mi < 4; ++mi) {
#pragma unroll
      for (int v = 0; v < 4; ++v) {
        int R = 128 * bi + 64 * wm + 16 * mi + 4 * q + v;
        float val = fmaxf(s[mi][nj][v] + bias, 0.0f);
        int mb = R >> 4;
        int lane2 = lane2hi | (R & 15);
        hfrag[((size_t)((mb * 16 + kkd) * 64 + lane2)) * 8 + j2] = f2bf(val);
      }
    }
  }
}

// --------------------- stage A2: lat_g = H_g@W2_g + b2 -----------------------
__global__ __launch_bounds__(256) void k_gemm2(
    const unsigned short* __restrict__ hfrag, const unsigned short* __restrict__ w2f,
    const float* __restrict__ b2_0, const float* __restrict__ b2_1,
    const float* __restrict__ b2_2, const float* __restrict__ b2_3,
    unsigned short* __restrict__ latf) {
  int bi = blockIdx.x, g = blockIdx.y;
  int lane = threadIdx.x & 63, w = threadIdx.x >> 6;
  int wm = w >> 1, wn = w & 1;
  int q = lane >> 4, r = lane & 15;
  int mbase = 8 * bi + 4 * wm;

  f32x4 s[4][4];
#pragma unroll
  for (int mi = 0; mi < 4; ++mi)
#pragma unroll
    for (int nj = 0; nj < 4; ++nj) s[mi][nj] = (f32x4){0.f, 0.f, 0.f, 0.f};

#pragma unroll
  for (int kk = 0; kk < 4; ++kk) {
    short8 a[4], b[4];
#pragma unroll
    for (int mi = 0; mi < 4; ++mi)
      a[mi] = *reinterpret_cast<const short8*>(
          hfrag + ((size_t)(((mbase + mi) * 16 + 4 * g + kk) * 64 + lane)) * 8);
#pragma unroll
    for (int nj = 0; nj < 4; ++nj)
      b[nj] = *reinterpret_cast<const short8*>(
          w2f + ((size_t)(((g * 4 + kk) * 8 + 4 * wn + nj) * 64 + lane)) * 8);
#pragma unroll
    for (int mi = 0; mi < 4; ++mi)
#pragma unroll
      for (int nj = 0; nj < 4; ++nj)
        s[mi][nj] = __builtin_amdgcn_mfma_f32_16x16x32_bf16(a[mi], b[nj], s[mi][nj], 0, 0, 0);
  }

  const float* b2 = g == 0 ? b2_0 : g == 1 ? b2_1 : g == 2 ? b2_2 : b2_3;
#pragma unroll
  for (int nj = 0; nj < 4; ++nj) {
    int cl = 64 * wn + 16 * nj + r;
    float bias = b2[cl];
    int kkd = cl >> 5;
    int lane2hi = ((cl >> 3) & 3) << 4;
    int j2 = cl & 7;
#pragma unroll
    for (int mi = 0; mi < 4; ++mi) {
#pragma unroll
      for (int v = 0; v < 4; ++v) {
        int R = 128 * bi + 64 * wm + 16 * mi + 4 * q + v;
        float val = s[mi][nj][v] + bias;
        int mb = R >> 4;
        int lane2 = lane2hi | (R & 15);
        latf[((size_t)(((g * 512 + mb) * 4 + kkd) * 64 + lane2)) * 8 + j2] = f2bf(val);
      }
    }
  }
}

// --------------------------- stage B: fused context --------------------------
// Block: 256 thr / 4 waves. Block tile = 16 rows (bi) x 2048 cols (strip cs),
// 32 steps of 64 cols; wave w owns col tile tj = cs*128 + s*4 + w per step.
// s = mfma(fj, fi): lane(q,r) reg v -> out(16*bi + r, 16*tj + 4q + v).
// fi: 16 frags in LDS (shared; filled once). fj: reg double-buffer via asm.
// ew: LDS triple buffer, 16 rows x 64 cols x 3 mats per step, filled 2 steps
// ahead, source col pre-swizzled by ^4*(row&7) floats for bank-even reads.

#define FJLD(dst, p, OFF) \
  asm volatile("global_load_dwordx4 %0, %1, off offset:" OFF : "=v"(dst) : "v"(p))

#define LOADFJ(F, TJ)                                                         \
  do {                                                                        \
    const unsigned short* _b = latf + (size_t)(TJ) * 2048 + (size_t)lane * 8; \
    FJLD(F[0][0], _b, "0");    FJLD(F[0][1], _b, "1024");                     \
    FJLD(F[0][2], _b, "2048"); FJLD(F[0][3], _b, "3072");                     \
    _b += GS;                                                                 \
    FJLD(F[1][0], _b, "0");    FJLD(F[1][1], _b, "1024");                     \
    FJLD(F[1][2], _b, "2048"); FJLD(F[1][3], _b, "3072");                     \
    _b += GS;                                                                 \
    FJLD(F[2][0], _b, "0");    FJLD(F[2][1], _b, "1024");                     \
    FJLD(F[2][2], _b, "2048"); FJLD(F[2][3], _b, "3072");                     \
    _b += GS;                                                                 \
    FJLD(F[3][0], _b, "0");    FJLD(F[3][1], _b, "1024");                     \
    FJLD(F[3][2], _b, "2048"); FJLD(F[3][3], _b, "3072");                     \
  } while (0)

#define GRAM(FC, G, OUTV)                                                     \
  do {                                                                        \
    short8 _f0 = ds_read_frag(fib + (G * 4 + 0) * 1024u + l16);               \
    short8 _f1 = ds_read_frag(fib + (G * 4 + 1) * 1024u + l16);               \
    short8 _f2 = ds_read_frag(fib + (G * 4 + 2) * 1024u + l16);               \
    short8 _f3 = ds_read_frag(fib + (G * 4 + 3) * 1024u + l16);               \
    asm volatile("s_waitcnt lgkmcnt(0)" ::: "memory");                        \
    __builtin_amdgcn_sched_barrier(0);                                        \
    f32x4 _sg = (f32x4){0.f, 0.f, 0.f, 0.f};                                  \
    _sg = __builtin_amdgcn_mfma_f32_16x16x32_bf16(FC[G][0], _f0, _sg, 0, 0, 0); \
    _sg = __builtin_amdgcn_mfma_f32_16x16x32_bf16(FC[G][1], _f1, _sg, 0, 0, 0); \
    _sg = __builtin_amdgcn_mfma_f32_16x16x32_bf16(FC[G][2], _f2, _sg, 0, 0, 0); \
    _sg = __builtin_amdgcn_mfma_f32_16x16x32_bf16(FC[G][3], _f3, _sg, 0, 0, 0); \
    OUTV = _sg;                                                               \
  } while (0)

#define STEP(S, FC, FN)                                                       \
  do {                                                                        \
    int _sn = ((S) + 1 < 32) ? (S) + 1 : 31;                                  \
    LOADFJ(FN, cs * 128 + _sn * 4 + w);                                       \
    __builtin_amdgcn_sched_barrier(0);                                        \
    {                                                                         \
      int _sf = ((S) + 2 < 32) ? (S) + 2 : 31;                                \
      fill_ew(_sf, ((S) + 2) % 3);                                            \
    }                                                                         \
    __builtin_amdgcn_sched_barrier(0);                                        \
    asm volatile("s_waitcnt vmcnt(23)" ::: "memory");                         \
    __builtin_amdgcn_sched_barrier(0);                                        \
    unsigned _ea = ewb + (unsigned)(((S) % 3) * 3072 + rdidx) * 4u;           \
    f32x4 ewa = ds_read_f32x4(_ea);                                           \
    f32x4 ewm = ds_read_f32x4(_ea + 4096u);                                   \
    f32x4 ewj = ds_read_f32x4(_ea + 8192u);                                   \
    f32x4 sg, o4;                                                             \
    GRAM(FC, 0, sg);                                                          \
    o4[0] = w0 * sigf(sg[0]); o4[1] = w0 * sigf(sg[1]);                       \
    o4[2] = w0 * sigf(sg[2]); o4[3] = w0 * sigf(sg[3]);                       \
    GRAM(FC, 1, sg);                                                          \
    o4[0] += w1 * sigf(sg[0] * ewa[0]); o4[1] += w1 * sigf(sg[1] * ewa[1]);   \
    o4[2] += w1 * sigf(sg[2] * ewa[2]); o4[3] += w1 * sigf(sg[3] * ewa[3]);   \
    GRAM(FC, 2, sg);                                                          \
    o4[0] += w2 * sigf(sg[0] * ewm[0]); o4[1] += w2 * sigf(sg[1] * ewm[1]);   \
    o4[2] += w2 * sigf(sg[2] * ewm[2]); o4[3] += w2 * sigf(sg[3] * ewm[3]);   \
    GRAM(FC, 3, sg);                                                          \
    f32x4 res;                                                                \
    { float u0 = sigf(sg[0]), u1 = sigf(sg[1]), u2 = sigf(sg[2]), u3 = sigf(sg[3]); \
      res[0] = ewj[0] * (o4[0] - u0) + u0; res[1] = ewj[1] * (o4[1] - u1) + u1; \
      res[2] = ewj[2] * (o4[2] - u2) + u2; res[3] = ewj[3] * (o4[3] - u3) + u3; } \
    {                                                                         \
      float* _op = out + (size_t)(bi * 16 + r) * 8192 + (size_t)cs * 2048     \
                   + (S) * 64 + 16 * w + 4 * q;                               \
      asm volatile("global_store_dwordx4 %0, %1, off" ::"v"(_op), "v"(res)    \
                   : "memory");                                               \
    }                                                                         \
    asm volatile("s_waitcnt vmcnt(21)" ::: "memory");                         \
    __builtin_amdgcn_s_barrier();                                             \
  } while (0)

__global__ __launch_bounds__(256, 2) void k_ctx(
    const unsigned short* __restrict__ latf,
    const float* __restrict__ adj, const float* __restrict__ aa,
    const float* __restrict__ mod, const float* __restrict__ wsv,
    float* __restrict__ out) {
  __shared__ unsigned short fi_lds[8192];   // 16 KB: 16 frags (4g x 4kk)
  __shared__ float ew_lds[3][3][1024];      // 36 KB: [tbuf][aa|mod|adj][16x64]

  const int bid = blockIdx.x;               // 2048 = 512 rowgroups x 4 strips
  const int cs = bid & 3;
  const int bi = bid >> 2;                  // 16-row block (0..511)
  const int lane = threadIdx.x & 63, w = threadIdx.x >> 6;
  const int q = lane >> 4, r = lane & 15;

  // softmax(ws)
  float s0w = wsv[0], s1w = wsv[1], s2w = wsv[2];
  float mx = fmaxf(fmaxf(s0w, s1w), s2w);
  float e0 = __builtin_amdgcn_exp2f(1.4426950408889634f * (s0w - mx));
  float e1 = __builtin_amdgcn_exp2f(1.4426950408889634f * (s1w - mx));
  float e2 = __builtin_amdgcn_exp2f(1.4426950408889634f * (s2w - mx));
  float inv = __builtin_amdgcn_rcpf(e0 + e1 + e2);
  float w0 = e0 * inv, w1 = e1 * inv, w2 = e2 * inv;

  const size_t GS = (size_t)512 * 2048;     // latf elements per latent

  // ew fill: wave w fills rows [4w,4w+4) of each matrix; 1 instr = 4 rows x
  // 256 B; source col pre-swizzled so LDS reads are bank-even.
  auto fill_ew = [&](int s2, int buf) {
    int rl = lane >> 4;                     // row within chunk (0..3)
    int fx = lane & 15;                     // 16B unit within row
    int lrow = 4 * w + rl;                  // tile row 0..15
    int scol = 4 * (fx ^ (lrow & 7));       // swizzled float col (0..60)
    size_t ga = (size_t)(bi * 16 + lrow) * 8192 + (size_t)cs * 2048
              + (size_t)s2 * 64 + scol;
    gload_lds16(aa + ga, &ew_lds[buf][0][w * 256]);
    gload_lds16(mod + ga, &ew_lds[buf][1][w * 256]);
    gload_lds16(adj + ga, &ew_lds[buf][2][w * 256]);
  };

  // ---- prologue ----
  // fi: wave w fills gram w's 4 frags (rows 16bi..16bi+15)
#pragma unroll
  for (int kk = 0; kk < 4; ++kk)
    gload_lds16u(latf + GS * w + (size_t)(bi * 4 + kk) * 512 + lane * 8,
                 &fi_lds[(w * 4 + kk) * 512]);
  fill_ew(0, 0);
  fill_ew(1, 1);

  short8 fjA[4][4], fjB[4][4];
  LOADFJ(fjA, cs * 128 + 0 * 4 + w);
  asm volatile("s_waitcnt vmcnt(0)" ::: "memory");
  __builtin_amdgcn_s_barrier();

  const unsigned fib = lds_off(fi_lds);
  const unsigned ewb = lds_off(&ew_lds[0][0][0]);
  const unsigned l16 = (unsigned)lane * 16u;
  // ew read float index: row r, logical col 16w+4q, phys col ^ 4*(r&7)
  const unsigned rdidx = (unsigned)(r * 64 + ((16 * w + 4 * q) ^ (4 * (r & 7))));

  for (int s = 0; s < 32; s += 2) {
    STEP(s, fjA, fjB);
    STEP(s + 1, fjB, fjA);
  }
}

// ------------------------------------------------------------------------------
extern "C" void kernel_launch(void* const* d_in, const int* in_sizes, int n_in,
                              void* d_out, int out_size, void* d_ws, size_t ws_size,
                              hipStream_t stream) {
  const float* feat = (const float*)d_in[0];
  const float* adj  = (const float*)d_in[1];
  const float* aa   = (const float*)d_in[2];
  const float* mod  = (const float*)d_in[3];
  // g order: 0=link, 1=aa, 2=mod, 3=unlink
  const float* W1g[4] = {(const float*)d_in[4], (const float*)d_in[12],
                         (const float*)d_in[16], (const float*)d_in[8]};
  const float* b1g[4] = {(const float*)d_in[5], (const float*)d_in[13],
                         (const float*)d_in[17], (const float*)d_in[9]};
  const float* W2g[4] = {(const float*)d_in[6], (const float*)d_in[14],
                         (const float*)d_in[18], (const float*)d_in[10]};
  const float* b2g[4] = {(const float*)d_in[7], (const float*)d_in[15],
                         (const float*)d_in[19], (const float*)d_in[11]};
  const float* wsv = (const float*)d_in[20];
  float* out = (float*)d_out;

  // workspace layout (elements of ushort)
  unsigned short* featf = (unsigned short*)d_ws;   // 4,194,304 elems (8 MiB)
  unsigned short* hfrag = featf + 4194304;         // 4,194,304
  unsigned short* latf  = hfrag + 4194304;         // 4,194,304
  unsigned short* w1f   = latf + 4194304;          //   262,144
  unsigned short* w2f   = w1f + 262144;            //    65,536
  if (ws_size < 25821184) return;

  k_featfrag<<<2048, 256, 0, stream>>>(feat, featf);
  k_wfrag<<<160, 256, 0, stream>>>(W1g[0], W1g[1], W1g[2], W1g[3],
                                   W2g[0], W2g[1], W2g[2], W2g[3], w1f, w2f);
  k_gemm1<<<dim3(64, 4), 256, 0, stream>>>(featf, w1f, b1g[0], b1g[1], b1g[2], b1g[3], hfrag);
  k_gemm2<<<dim3(64, 4), 256, 0, stream>>>(hfrag, w2f, b2g[0], b2g[1], b2g[2], b2g[3], latf);
  k_ctx<<<2048, 256, 0, stream>>>(latf, adj, aa, mod, wsv, out);
}